// Round 1
// baseline (203.112 us; speedup 1.0000x reference)
//
#include <hip/hip_runtime.h>

#define N_FEATURES 4096
#define N_GROUPS   1024
#define BATCH      8192

// Kernel 1: coeff[f] = sum over entries i with flat_idx[i]==f of
//           w_flat[i] * diag_w[seg_ids[i]] * dense_W[seg_ids[i]]
// Single block; coeff accumulated in LDS with atomics, then written out.
__global__ __launch_bounds__(1024) void build_coeff_kernel(
    const int* __restrict__ flat_idx,
    const int* __restrict__ seg_ids,
    const float* __restrict__ w_flat,
    const float* __restrict__ diag_w,
    const float* __restrict__ dense_W,
    float* __restrict__ coeff,
    int total)
{
    __shared__ float s_coeff[N_FEATURES];
    for (int i = threadIdx.x; i < N_FEATURES; i += blockDim.x) s_coeff[i] = 0.0f;
    __syncthreads();
    for (int i = threadIdx.x; i < total; i += blockDim.x) {
        int g = seg_ids[i];
        float c = w_flat[i] * diag_w[g] * dense_W[g];
        atomicAdd(&s_coeff[flat_idx[i]], c);
    }
    __syncthreads();
    for (int i = threadIdx.x; i < N_FEATURES; i += blockDim.x) coeff[i] = s_coeff[i];
}

// Kernel 2: out[b] = dot(x[b,:], coeff).  One 256-thread block per row.
// 4096 floats/row = 1024 float4; 256 threads x 4 float4 each, fully coalesced.
__global__ __launch_bounds__(256) void gemv_kernel(
    const float* __restrict__ x,
    const float* __restrict__ coeff,
    float* __restrict__ out)
{
    const int row = blockIdx.x;
    const float4* __restrict__ xr = (const float4*)(x + (size_t)row * N_FEATURES);
    const float4* __restrict__ c4 = (const float4*)coeff;

    float acc = 0.0f;
#pragma unroll
    for (int k = 0; k < 4; ++k) {
        int i = k * 256 + threadIdx.x;
        float4 xv = xr[i];
        float4 cv = c4[i];
        acc += xv.x * cv.x + xv.y * cv.y + xv.z * cv.z + xv.w * cv.w;
    }

    // wave (64-lane) shuffle reduction
#pragma unroll
    for (int off = 32; off > 0; off >>= 1)
        acc += __shfl_down(acc, off, 64);

    __shared__ float s_part[4];
    const int lane = threadIdx.x & 63;
    const int wid  = threadIdx.x >> 6;
    if (lane == 0) s_part[wid] = acc;
    __syncthreads();
    if (threadIdx.x == 0)
        out[row] = s_part[0] + s_part[1] + s_part[2] + s_part[3];
}

extern "C" void kernel_launch(void* const* d_in, const int* in_sizes, int n_in,
                              void* d_out, int out_size, void* d_ws, size_t ws_size,
                              hipStream_t stream) {
    const float* x        = (const float*)d_in[0];  // [BATCH, N_FEATURES]
    const int*   flat_idx = (const int*)d_in[1];    // [total]
    const int*   seg_ids  = (const int*)d_in[2];    // [total]
    const float* w_flat   = (const float*)d_in[3];  // [total]
    const float* diag_w   = (const float*)d_in[4];  // [N_GROUPS]
    const float* dense_W  = (const float*)d_in[5];  // [N_GROUPS]
    float* out = (float*)d_out;                     // [BATCH] (shape [BATCH,1])
    const int total = in_sizes[1];

    float* coeff = (float*)d_ws;  // N_FEATURES floats

    build_coeff_kernel<<<1, 1024, 0, stream>>>(flat_idx, seg_ids, w_flat,
                                               diag_w, dense_W, coeff, total);
    gemv_kernel<<<BATCH, 256, 0, stream>>>(x, coeff, out);
}